// Round 1
// baseline (271.474 us; speedup 1.0000x reference)
//
#include <hip/hip_runtime.h>

typedef __bf16 bf16x8 __attribute__((ext_vector_type(8)));
typedef float f32x4 __attribute__((ext_vector_type(4)));

#define MFMA16 __builtin_amdgcn_mfma_f32_16x16x32_bf16

__device__ __forceinline__ unsigned short f2b(float f) {
  unsigned int u = __float_as_uint(f);
  u += 0x7FFFu + ((u >> 16) & 1u);
  return (unsigned short)(u >> 16);
}

union U128 {
  uint4 u;
  unsigned short s[8];
  bf16x8 b;
};

// ---------------- projection: f = wq x, g = wk x, h = wv x ----------------
// f_t/g_t stored transposed [B][N][8] bf16 (one MFMA fragment = one 16B row),
// h stored [B][64][N] bf16.
__global__ __launch_bounds__(256) void proj_kernel(
    const float* __restrict__ x, const float* __restrict__ wq,
    const float* __restrict__ wk, const float* __restrict__ wv,
    unsigned short* __restrict__ f_t, unsigned short* __restrict__ g_t,
    unsigned short* __restrict__ h_out) {
  const int idx = blockIdx.x * 256 + threadIdx.x;  // (b,n), 0..32767
  const int b = idx >> 12;
  const int n = idx & 4095;
  const float* xb = x + ((size_t)b << 18) + n;  // x[b][0][n]

  float xc[64];
#pragma unroll
  for (int c = 0; c < 64; ++c) xc[c] = xb[(size_t)c << 12];

  U128 fu, gu;
#pragma unroll
  for (int k = 0; k < 8; ++k) {
    float fa = 0.f, ga = 0.f;
#pragma unroll
    for (int c = 0; c < 64; ++c) {
      fa += wq[k * 64 + c] * xc[c];
      ga += wk[k * 64 + c] * xc[c];
    }
    fu.s[k] = f2b(fa);
    gu.s[k] = f2b(ga);
  }
  *(uint4*)(f_t + ((size_t)idx << 3)) = fu.u;
  *(uint4*)(g_t + ((size_t)idx << 3)) = gu.u;

#pragma unroll 2
  for (int o = 0; o < 64; ++o) {
    float ha = 0.f;
#pragma unroll
    for (int c = 0; c < 64; ++c) ha += wv[o * 64 + c] * xc[c];
    h_out[(((size_t)b * 64 + o) << 12) + n] = f2b(ha);
  }
}

// ---------------- flash attention ----------------
// grid: 512 = B * (N/64).  block: 256 (4 waves).  wave w owns m-subtile of 16.
// Per n-tile of 64: S = F^T G via MFMA (K padded 8->32 with zero B-quads),
// P = exp(S) -> LDS round trip (C-layout -> B-layout), O += H P via MFMA.
// No max subtraction (|s| <~ 35, exp fits fp32 comfortably).
__global__ __launch_bounds__(256) void attn_kernel(
    const unsigned short* __restrict__ f_t, const unsigned short* __restrict__ g_t,
    const unsigned short* __restrict__ h, const float* __restrict__ x,
    const float* __restrict__ gamma, float* __restrict__ out) {
  // wave-private P buffers, parity double-buffered: [par][wave][m 16][n 64 pad 80]
  __shared__ unsigned short P_lds[2][4][16][80];

  const int tid = (int)threadIdx.x;
  const int wave = tid >> 6;
  const int lane = tid & 63;
  const int q = lane >> 4;   // quad
  const int t = lane & 15;   // row/col index within fragment

  const int b = (int)blockIdx.x >> 6;
  const int m0 = ((int)blockIdx.x & 63) << 6;
  const int m = m0 + wave * 16 + t;  // this lane's output column

  // G fragment (B operand of score MFMA): B[k][m] = g^T[m][k], zeros for k>=8
  U128 gu;
  gu.u = make_uint4(0u, 0u, 0u, 0u);
  if (q == 0) gu.u = *(const uint4*)(g_t + ((size_t)(b * 4096 + m) << 3));

  f32x4 O0 = {0.f, 0.f, 0.f, 0.f};
  f32x4 O1 = {0.f, 0.f, 0.f, 0.f};
  f32x4 O2 = {0.f, 0.f, 0.f, 0.f};
  f32x4 O3 = {0.f, 0.f, 0.f, 0.f};
  float lpart = 0.f;

  const unsigned short* fb = f_t + ((size_t)b << 15);  // b*4096*8
  const unsigned short* hb = h + ((size_t)b << 18);    // b*64*4096

#pragma unroll 2
  for (int n0 = 0; n0 < 4096; n0 += 64) {
    const int par = (n0 >> 6) & 1;

    // F A-fragments: A[n][k] = f^T[n][k]; all quads load row (broadcast),
    // garbage in k>=8 positions is multiplied by zero G-quads.
    U128 fA0, fA1, fA2, fA3;
    fA0.u = *(const uint4*)(fb + ((size_t)(n0 + t) << 3));
    fA1.u = *(const uint4*)(fb + ((size_t)(n0 + 16 + t) << 3));
    fA2.u = *(const uint4*)(fb + ((size_t)(n0 + 32 + t) << 3));
    fA3.u = *(const uint4*)(fb + ((size_t)(n0 + 48 + t) << 3));

    // H A-fragments: A[c][n], c = cb*16 + t, n = n0 + ch*32 + q*8 + j
    const unsigned short* hrow = hb + ((size_t)(t) << 12) + n0 + q * 8;
    U128 h00, h01, h10, h11, h20, h21, h30, h31;
    h00.u = *(const uint4*)(hrow + (0 << 16) + 0);
    h01.u = *(const uint4*)(hrow + (0 << 16) + 32);
    h10.u = *(const uint4*)(hrow + (1 << 16) + 0);
    h11.u = *(const uint4*)(hrow + (1 << 16) + 32);
    h20.u = *(const uint4*)(hrow + (2 << 16) + 0);
    h21.u = *(const uint4*)(hrow + (2 << 16) + 32);
    h30.u = *(const uint4*)(hrow + (3 << 16) + 0);
    h31.u = *(const uint4*)(hrow + (3 << 16) + 32);

    const f32x4 z = {0.f, 0.f, 0.f, 0.f};
    f32x4 s0 = MFMA16(fA0.b, gu.b, z, 0, 0, 0);
    f32x4 s1 = MFMA16(fA1.b, gu.b, z, 0, 0, 0);
    f32x4 s2 = MFMA16(fA2.b, gu.b, z, 0, 0, 0);
    f32x4 s3 = MFMA16(fA3.b, gu.b, z, 0, 0, 0);

    // exp, denominator partial, pack to bf16, write P[m][n] rows
    {
      float e0 = __expf(s0[0]), e1 = __expf(s0[1]), e2 = __expf(s0[2]), e3 = __expf(s0[3]);
      lpart += (e0 + e1) + (e2 + e3);
      uint2 w;
      w.x = (unsigned)f2b(e0) | ((unsigned)f2b(e1) << 16);
      w.y = (unsigned)f2b(e2) | ((unsigned)f2b(e3) << 16);
      *(uint2*)&P_lds[par][wave][t][0 + q * 4] = w;
    }
    {
      float e0 = __expf(s1[0]), e1 = __expf(s1[1]), e2 = __expf(s1[2]), e3 = __expf(s1[3]);
      lpart += (e0 + e1) + (e2 + e3);
      uint2 w;
      w.x = (unsigned)f2b(e0) | ((unsigned)f2b(e1) << 16);
      w.y = (unsigned)f2b(e2) | ((unsigned)f2b(e3) << 16);
      *(uint2*)&P_lds[par][wave][t][16 + q * 4] = w;
    }
    {
      float e0 = __expf(s2[0]), e1 = __expf(s2[1]), e2 = __expf(s2[2]), e3 = __expf(s2[3]);
      lpart += (e0 + e1) + (e2 + e3);
      uint2 w;
      w.x = (unsigned)f2b(e0) | ((unsigned)f2b(e1) << 16);
      w.y = (unsigned)f2b(e2) | ((unsigned)f2b(e3) << 16);
      *(uint2*)&P_lds[par][wave][t][32 + q * 4] = w;
    }
    {
      float e0 = __expf(s3[0]), e1 = __expf(s3[1]), e2 = __expf(s3[2]), e3 = __expf(s3[3]);
      lpart += (e0 + e1) + (e2 + e3);
      uint2 w;
      w.x = (unsigned)f2b(e0) | ((unsigned)f2b(e1) << 16);
      w.y = (unsigned)f2b(e2) | ((unsigned)f2b(e3) << 16);
      *(uint2*)&P_lds[par][wave][t][48 + q * 4] = w;
    }

    __syncthreads();

    // P B-fragments: B[n][m], row t (=this lane's m), 16B contiguous in n
    U128 p0, p1;
    p0.u = *(const uint4*)&P_lds[par][wave][t][q * 8];
    p1.u = *(const uint4*)&P_lds[par][wave][t][32 + q * 8];

    O0 = MFMA16(h00.b, p0.b, O0, 0, 0, 0);
    O0 = MFMA16(h01.b, p1.b, O0, 0, 0, 0);
    O1 = MFMA16(h10.b, p0.b, O1, 0, 0, 0);
    O1 = MFMA16(h11.b, p1.b, O1, 0, 0, 0);
    O2 = MFMA16(h20.b, p0.b, O2, 0, 0, 0);
    O2 = MFMA16(h21.b, p1.b, O2, 0, 0, 0);
    O3 = MFMA16(h30.b, p0.b, O3, 0, 0, 0);
    O3 = MFMA16(h31.b, p1.b, O3, 0, 0, 0);
  }

  // denominator: lane holds rows {n : (n mod 16) in [q*4, q*4+4)}; sum quads
  float l = lpart;
  l += __shfl_xor(l, 16, 64);
  l += __shfl_xor(l, 32, 64);
  const float scale = gamma[0] / l;

  // epilogue: out[b][c][m] = scale * O[c][m] + x[b][c][m]
#pragma unroll
  for (int cb = 0; cb < 4; ++cb) {
    const f32x4 Ov = (cb == 0) ? O0 : (cb == 1) ? O1 : (cb == 2) ? O2 : O3;
#pragma unroll
    for (int r = 0; r < 4; ++r) {
      const int c = cb * 16 + q * 4 + r;
      const size_t oi = (((size_t)b * 64 + c) << 12) + m;
      out[oi] = scale * Ov[r] + x[oi];
    }
  }
}

extern "C" void kernel_launch(void* const* d_in, const int* in_sizes, int n_in,
                              void* d_out, int out_size, void* d_ws, size_t ws_size,
                              hipStream_t stream) {
  (void)in_sizes; (void)n_in; (void)out_size; (void)ws_size;
  const float* x = (const float*)d_in[0];
  const float* wq = (const float*)d_in[1];
  const float* wk = (const float*)d_in[2];
  const float* wv = (const float*)d_in[3];
  const float* gamma = (const float*)d_in[4];
  float* out = (float*)d_out;

  // workspace: f_t [8][4096][8] bf16, g_t same, h [8][64][4096] bf16 = 5.25 MB
  unsigned short* f_t = (unsigned short*)d_ws;
  unsigned short* g_t = f_t + (size_t)8 * 4096 * 8;
  unsigned short* h = g_t + (size_t)8 * 4096 * 8;

  proj_kernel<<<128, 256, 0, stream>>>(x, wq, wk, wv, f_t, g_t, h);
  attn_kernel<<<512, 256, 0, stream>>>(f_t, g_t, h, x, gamma, out);
}

// Round 2
// 219.263 us; speedup vs baseline: 1.2381x; 1.2381x over previous
//
#include <hip/hip_runtime.h>
#include <hip/hip_bf16.h>

typedef __bf16 bf16x8 __attribute__((ext_vector_type(8)));
typedef float f32x4 __attribute__((ext_vector_type(4)));

#define MFMA16 __builtin_amdgcn_mfma_f32_16x16x32_bf16

__device__ __forceinline__ unsigned short f2b(float f) {
  unsigned int u = __float_as_uint(f);
  u += 0x7FFFu + ((u >> 16) & 1u);
  return (unsigned short)(u >> 16);
}

union U128 {
  uint4 u;
  unsigned short s[8];
  bf16x8 b;
};

union BPack {
  __hip_bfloat162 h2;
  unsigned u;
};

// ---------------- projection: f = wq x, g = wk x, h = wv x ----------------
// grid 512 = B * N/64, block 320 (5 waves). lane = column within 64-tile.
// wave 0: f,g rows (8+8). waves 1..4: h rows (w-1)*16 .. +16.
// f_t/g_t stored transposed [B][N][8] bf16; h stored [B][64][N] bf16.
__global__ __launch_bounds__(320) void proj_kernel(
    const float* __restrict__ x, const float* __restrict__ wq,
    const float* __restrict__ wk, const float* __restrict__ wv,
    unsigned short* __restrict__ f_t, unsigned short* __restrict__ g_t,
    unsigned short* __restrict__ h_out) {
  const int tid = (int)threadIdx.x;
  const int wave = tid >> 6;
  const int lane = tid & 63;
  const int b = (int)blockIdx.x >> 6;
  const int n = (((int)blockIdx.x & 63) << 6) + lane;
  const float* xb = x + ((size_t)b << 18) + n;

  float xc[64];
#pragma unroll
  for (int c = 0; c < 64; ++c) xc[c] = xb[(size_t)c << 12];

  if (wave == 0) {
    U128 fu, gu;
#pragma unroll
    for (int k = 0; k < 8; ++k) {
      float fa = 0.f, ga = 0.f;
#pragma unroll
      for (int c = 0; c < 64; ++c) {
        fa += wq[k * 64 + c] * xc[c];
        ga += wk[k * 64 + c] * xc[c];
      }
      fu.s[k] = f2b(fa);
      gu.s[k] = f2b(ga);
    }
    const int idx = (b << 12) + n;
    *(uint4*)(f_t + ((size_t)idx << 3)) = fu.u;
    *(uint4*)(g_t + ((size_t)idx << 3)) = gu.u;
  } else {
    const int o0 = (wave - 1) << 4;
#pragma unroll 4
    for (int o = 0; o < 16; ++o) {
      float ha = 0.f;
#pragma unroll
      for (int c = 0; c < 64; ++c) ha += wv[(o0 + o) * 64 + c] * xc[c];
      h_out[(((size_t)b * 64 + o0 + o) << 12) + n] = f2b(ha);
    }
  }
}

// ---------------- flash attention ----------------
// grid 512 = B * N/64 (m-tiles), block 256 (4 waves), wave owns 16 m-cols.
// No __syncthreads: P LDS buffers are wave-private; DS ops are in-order per
// wave, so a compiler-only memory clobber is sufficient ordering. Parity
// double-buffer makes cross-iteration compiler reordering harmless.
// Software pipeline: tile i+1's global loads issue before tile i's compute.
__global__ __launch_bounds__(256) void attn_kernel(
    const unsigned short* __restrict__ f_t, const unsigned short* __restrict__ g_t,
    const unsigned short* __restrict__ h, const float* __restrict__ x,
    const float* __restrict__ gamma, float* __restrict__ out) {
  // stride 72 shorts = 36 dwords === 4 (mod 32): bank-uniform for b64 writes
  // and b128 reads (4-touch/bank min both).
  __shared__ unsigned short P_lds[2][4][16][72];

  const int tid = (int)threadIdx.x;
  const int wave = tid >> 6;
  const int lane = tid & 63;
  const int q = lane >> 4;
  const int t = lane & 15;

  const int b = (int)blockIdx.x >> 6;
  const int m = (((int)blockIdx.x & 63) << 6) + wave * 16 + t;

  // G fragment (B operand of score MFMA): B[k][m], zeros for k>=8
  U128 gu;
  gu.u = make_uint4(0u, 0u, 0u, 0u);
  if (q == 0) gu.u = *(const uint4*)(g_t + ((size_t)((b << 12) + m) << 3));

  f32x4 O[4];
#pragma unroll
  for (int i = 0; i < 4; ++i) O[i] = (f32x4){0.f, 0.f, 0.f, 0.f};
  float lpart = 0.f;

  const unsigned short* fb = f_t + ((size_t)b << 15);
  const unsigned short* hb = h + ((size_t)b << 18);

  U128 Fa[4], Ha[8];
  // prologue: load tile 0
#pragma unroll
  for (int s = 0; s < 4; ++s)
    Fa[s].u = *(const uint4*)(fb + ((size_t)(16 * s + t) << 3));
  {
    const unsigned short* hrow = hb + ((size_t)t << 12) + q * 8;
#pragma unroll
    for (int cb = 0; cb < 4; ++cb) {
      Ha[2 * cb + 0].u = *(const uint4*)(hrow + (cb << 16) + 0);
      Ha[2 * cb + 1].u = *(const uint4*)(hrow + (cb << 16) + 32);
    }
  }

#pragma unroll 2
  for (int i = 0; i < 64; ++i) {
    const int par = i & 1;
    const int nn = ((i + 1) << 6) & 4095;  // wraps to 0 on last iter (unused)

    // ---- prefetch next tile ----
    U128 Fn[4], Hn[8];
#pragma unroll
    for (int s = 0; s < 4; ++s)
      Fn[s].u = *(const uint4*)(fb + ((size_t)(nn + 16 * s + t) << 3));
    {
      const unsigned short* hrow = hb + ((size_t)t << 12) + nn + q * 8;
#pragma unroll
      for (int cb = 0; cb < 4; ++cb) {
        Hn[2 * cb + 0].u = *(const uint4*)(hrow + (cb << 16) + 0);
        Hn[2 * cb + 1].u = *(const uint4*)(hrow + (cb << 16) + 32);
      }
    }

    // ---- scores: S[n_local][m] ----
    const f32x4 z = {0.f, 0.f, 0.f, 0.f};
    f32x4 ss[4];
#pragma unroll
    for (int s = 0; s < 4; ++s) ss[s] = MFMA16(Fa[s].b, gu.b, z, 0, 0, 0);

    // ---- exp, denominator partial, pack to bf16, LDS write P[m][n] ----
#pragma unroll
    for (int s = 0; s < 4; ++s) {
      float e0 = __expf(ss[s][0]), e1 = __expf(ss[s][1]);
      float e2 = __expf(ss[s][2]), e3 = __expf(ss[s][3]);
      lpart += (e0 + e1) + (e2 + e3);
      BPack lo, hi;
      lo.h2 = __float22bfloat162_rn(make_float2(e0, e1));
      hi.h2 = __float22bfloat162_rn(make_float2(e2, e3));
      uint2 w;
      w.x = lo.u;
      w.y = hi.u;
      *(uint2*)&P_lds[par][wave][t][16 * s + 4 * q] = w;
    }

    // compiler-only ordering; DS ops are in-order per wave at HW level
    __asm__ volatile("" ::: "memory");

    // ---- P B-fragments and PV MFMAs ----
    U128 p0, p1;
    p0.u = *(const uint4*)&P_lds[par][wave][t][8 * q];
    p1.u = *(const uint4*)&P_lds[par][wave][t][32 + 8 * q];

#pragma unroll
    for (int cb = 0; cb < 4; ++cb) {
      O[cb] = MFMA16(Ha[2 * cb + 0].b, p0.b, O[cb], 0, 0, 0);
      O[cb] = MFMA16(Ha[2 * cb + 1].b, p1.b, O[cb], 0, 0, 0);
    }

    // ---- rotate staging registers ----
#pragma unroll
    for (int s = 0; s < 4; ++s) Fa[s] = Fn[s];
#pragma unroll
    for (int j = 0; j < 8; ++j) Ha[j] = Hn[j];
  }

  // denominator: sum quads (lane holds rows n===q*4+r mod 16 across tiles)
  float l = lpart;
  l += __shfl_xor(l, 16, 64);
  l += __shfl_xor(l, 32, 64);
  const float scale = gamma[0] / l;

  // epilogue: out[b][c][m] = scale * O[c][m] + x[b][c][m]
#pragma unroll
  for (int cb = 0; cb < 4; ++cb) {
#pragma unroll
    for (int r = 0; r < 4; ++r) {
      const int c = cb * 16 + q * 4 + r;
      const size_t oi = (((size_t)b * 64 + c) << 12) + m;
      out[oi] = scale * O[cb][r] + x[oi];
    }
  }
}

extern "C" void kernel_launch(void* const* d_in, const int* in_sizes, int n_in,
                              void* d_out, int out_size, void* d_ws, size_t ws_size,
                              hipStream_t stream) {
  (void)in_sizes; (void)n_in; (void)out_size; (void)ws_size;
  const float* x = (const float*)d_in[0];
  const float* wq = (const float*)d_in[1];
  const float* wk = (const float*)d_in[2];
  const float* wv = (const float*)d_in[3];
  const float* gamma = (const float*)d_in[4];
  float* out = (float*)d_out;

  // workspace: f_t [8][4096][8] bf16, g_t same, h [8][64][4096] bf16 = 5.25 MB
  unsigned short* f_t = (unsigned short*)d_ws;
  unsigned short* g_t = f_t + (size_t)8 * 4096 * 8;
  unsigned short* h = g_t + (size_t)8 * 4096 * 8;

  proj_kernel<<<512, 320, 0, stream>>>(x, wq, wk, wv, f_t, g_t, h);
  attn_kernel<<<512, 256, 0, stream>>>(f_t, g_t, h, x, gamma, out);
}

// Round 3
// 219.155 us; speedup vs baseline: 1.2387x; 1.0005x over previous
//
#include <hip/hip_runtime.h>
#include <hip/hip_bf16.h>

typedef __bf16 bf16x8 __attribute__((ext_vector_type(8)));
typedef float f32x16 __attribute__((ext_vector_type(16)));

#define MFMA32 __builtin_amdgcn_mfma_f32_32x32x16_bf16

__device__ __forceinline__ unsigned short f2b(float f) {
  unsigned int u = __float_as_uint(f);
  u += 0x7FFFu + ((u >> 16) & 1u);
  return (unsigned short)(u >> 16);
}

union U128 {
  uint4 u;
  unsigned short s[8];
  bf16x8 b;
};

union BPack {
  __hip_bfloat162 h2;
  unsigned u;
};

// ---------------- projection ----------------
// grid 512 = B * N/64 (XCD-swizzled), block 256 (4 waves).
// Stage x tile [64c][64n] fp32 in LDS; wave w computes 20 of the 80 output
// rows (f:0-7, g:8-15, h:16-79) with fp32 acc in registers, weights via
// uniform scalar loads. No per-thread 64-deep arrays -> no scratch spills.
__global__ __launch_bounds__(256, 4) void proj_kernel(
    const float* __restrict__ x, const float* __restrict__ wq,
    const float* __restrict__ wk, const float* __restrict__ wv,
    unsigned short* __restrict__ f_t, unsigned short* __restrict__ g_t,
    unsigned short* __restrict__ h_out) {
  __shared__ float xs[64][64];  // bank = lane%32 -> 2-way (free)

  const int tid = (int)threadIdx.x;
  const int wave = tid >> 6;
  const int lane = tid & 63;
  const int b = (int)blockIdx.x & 7;
  const int n0 = ((int)blockIdx.x >> 3) << 6;
  const float* xb = x + ((size_t)b << 18) + n0 + lane;

#pragma unroll
  for (int i = 0; i < 16; ++i) {
    const int c = wave + i * 4;
    xs[c][lane] = xb[(size_t)c << 12];
  }
  __syncthreads();

  float acc[20];
#pragma unroll
  for (int r = 0; r < 20; ++r) acc[r] = 0.f;

#pragma unroll 2
  for (int c8 = 0; c8 < 64; c8 += 8) {
    float xv[8];
#pragma unroll
    for (int j = 0; j < 8; ++j) xv[j] = xs[c8 + j][lane];
#pragma unroll
    for (int rr = 0; rr < 20; ++rr) {
      const int r = wave * 20 + rr;
      const float* wrow = (r < 8) ? (wq + r * 64)
                        : (r < 16) ? (wk + (r - 8) * 64)
                                   : (wv + (r - 16) * 64);
#pragma unroll
      for (int j = 0; j < 8; ++j) acc[rr] += wrow[c8 + j] * xv[j];
    }
  }

#pragma unroll
  for (int rr = 0; rr < 20; ++rr) {
    const int r = wave * 20 + rr;
    const unsigned short v = f2b(acc[rr]);
    if (r < 8)
      f_t[(size_t)((b << 12) + n0 + lane) * 8 + r] = v;
    else if (r < 16)
      g_t[(size_t)((b << 12) + n0 + lane) * 8 + (r - 8)] = v;
    else
      h_out[(((size_t)b * 64 + (r - 16)) << 12) + n0 + lane] = v;
  }
}

// ---------------- flash attention, producer/consumer ----------------
// grid 512 = B * N/64 m-tiles (b = blk&7 -> XCD-local batch), block 512
// (8 waves). Producers (0-3): one 32x32x16 score MFMA (nh=w&1, mh=w>>1),
// exp, pack, write P[m 64][n 64] bf16 to LDS (parity double-buffer, one
// barrier/tile). Consumers (4-7): own 32c x 32m O tile; 4 H fragments from
// global (no redundancy within block), 4 ds_read_b128 P fragments
// (bank-uniform), 4 PV MFMAs. K of score dot padded 8->16 via zero G half.
__global__ __launch_bounds__(512, 4) void attn_kernel(
    const unsigned short* __restrict__ f_t, const unsigned short* __restrict__ g_t,
    const unsigned short* __restrict__ h, const float* __restrict__ x,
    const float* __restrict__ gamma, float* __restrict__ out) {
  __shared__ unsigned short P_lds[2][64][72];  // 18 KB, stride 36 dw
  __shared__ float lred[4][32];

  const int tid = (int)threadIdx.x;
  const int wave = tid >> 6;
  const int lane = tid & 63;
  const int ml = lane & 31;  // row/col within 32-fragment
  const int hh = lane >> 5;  // k-half

  const int b = (int)blockIdx.x & 7;
  const int m0 = ((int)blockIdx.x >> 3) << 6;

  const unsigned short* fb = f_t + ((size_t)b << 15);
  const unsigned short* hb = h + ((size_t)b << 18);

  if (wave < 4) {
    // ================= producer =================
    const int nh = wave & 1, mh = wave >> 1;
    U128 G;
    G.u = make_uint4(0u, 0u, 0u, 0u);
    if (hh == 0)
      G.u = *(const uint4*)(g_t + ((size_t)((b << 12) + m0 + mh * 32 + ml) << 3));

    U128 Fa, Fn;
    Fa.u = *(const uint4*)(fb + ((size_t)(nh * 32 + ml) << 3));
    float lp = 0.f;

#pragma unroll 2
    for (int i = 0; i <= 64; ++i) {
      if (i < 64) {
        const int nnext = (((i + 1) & 63) << 6) + nh * 32 + ml;
        Fn.u = *(const uint4*)(fb + ((size_t)nnext << 3));

        f32x16 zz = {};
        f32x16 S = MFMA32(Fa.b, G.b, zz, 0, 0, 0);

        unsigned short* prow = &P_lds[i & 1][mh * 32 + ml][nh * 32 + 4 * hh];
#pragma unroll
        for (int g2 = 0; g2 < 4; ++g2) {
          float e0 = __expf(S[4 * g2 + 0]);
          float e1 = __expf(S[4 * g2 + 1]);
          float e2 = __expf(S[4 * g2 + 2]);
          float e3 = __expf(S[4 * g2 + 3]);
          lp += (e0 + e1) + (e2 + e3);
          BPack lo, hi;
          lo.h2 = __float22bfloat162_rn(make_float2(e0, e1));
          hi.h2 = __float22bfloat162_rn(make_float2(e2, e3));
          uint2 w2;
          w2.x = lo.u;
          w2.y = hi.u;
          *(uint2*)(prow + 8 * g2) = w2;
        }
        Fa = Fn;
      } else {
        float v = lp + __shfl_xor(lp, 32, 64);
        if (hh == 0) lred[wave][ml] = v;
      }
      __syncthreads();
    }
  } else {
    // ================= consumer =================
    const int cw = wave - 4;
    const int chc = cw & 1, mh = cw >> 1;
    const unsigned short* hrow = hb + ((size_t)(chc * 32 + ml) << 12) + 8 * hh;

    f32x16 O = {};
    U128 Ha[4], Hn[4];

#pragma unroll 2
    for (int i = 0; i <= 64; ++i) {
      if (i < 64) {
#pragma unroll
        for (int kk = 0; kk < 4; ++kk)
          Hn[kk].u = *(const uint4*)(hrow + (i << 6) + kk * 16);
      }
      if (i >= 1) {
        const int par = (i - 1) & 1;
        U128 p0, p1, p2, p3;
        p0.u = *(const uint4*)&P_lds[par][mh * 32 + ml][0 + 8 * hh];
        p1.u = *(const uint4*)&P_lds[par][mh * 32 + ml][16 + 8 * hh];
        p2.u = *(const uint4*)&P_lds[par][mh * 32 + ml][32 + 8 * hh];
        p3.u = *(const uint4*)&P_lds[par][mh * 32 + ml][48 + 8 * hh];
        O = MFMA32(Ha[0].b, p0.b, O, 0, 0, 0);
        O = MFMA32(Ha[1].b, p1.b, O, 0, 0, 0);
        O = MFMA32(Ha[2].b, p2.b, O, 0, 0, 0);
        O = MFMA32(Ha[3].b, p3.b, O, 0, 0, 0);
      }
#pragma unroll
      for (int kk = 0; kk < 4; ++kk) Ha[kk] = Hn[kk];
      __syncthreads();
    }

    // epilogue: out[b][c][m] = gamma/l[m] * O + x
    const float sc = gamma[0] / (lred[2 * mh][ml] + lred[2 * mh + 1][ml]);
#pragma unroll
    for (int reg = 0; reg < 16; ++reg) {
      const int c = chc * 32 + (reg & 3) + 8 * (reg >> 2) + 4 * hh;
      const size_t oi = (((size_t)b * 64 + c) << 12) + m0 + mh * 32 + ml;
      out[oi] = sc * O[reg] + x[oi];
    }
  }
}

extern "C" void kernel_launch(void* const* d_in, const int* in_sizes, int n_in,
                              void* d_out, int out_size, void* d_ws, size_t ws_size,
                              hipStream_t stream) {
  (void)in_sizes; (void)n_in; (void)out_size; (void)ws_size;
  const float* x = (const float*)d_in[0];
  const float* wq = (const float*)d_in[1];
  const float* wk = (const float*)d_in[2];
  const float* wv = (const float*)d_in[3];
  const float* gamma = (const float*)d_in[4];
  float* out = (float*)d_out;

  // workspace: f_t [8][4096][8] bf16, g_t same, h [8][64][4096] bf16 = 5.25 MB
  unsigned short* f_t = (unsigned short*)d_ws;
  unsigned short* g_t = f_t + (size_t)8 * 4096 * 8;
  unsigned short* h = g_t + (size_t)8 * 4096 * 8;

  proj_kernel<<<512, 256, 0, stream>>>(x, wq, wk, wv, f_t, g_t, h);
  attn_kernel<<<512, 512, 0, stream>>>(f_t, g_t, h, x, gamma, out);
}

// Round 4
// 148.712 us; speedup vs baseline: 1.8255x; 1.4737x over previous
//
#include <hip/hip_runtime.h>
#include <hip/hip_bf16.h>

typedef __bf16 bf16x8 __attribute__((ext_vector_type(8)));
typedef float f32x16 __attribute__((ext_vector_type(16)));

#define MFMA32 __builtin_amdgcn_mfma_f32_32x32x16_bf16

__device__ __forceinline__ unsigned short f2b(float f) {
  unsigned int u = __float_as_uint(f);
  u += 0x7FFFu + ((u >> 16) & 1u);
  return (unsigned short)(u >> 16);
}

union U128 {
  uint4 u;
  unsigned short s[8];
  bf16x8 b;
};

union BPack {
  __hip_bfloat162 h2;
  unsigned u;
};

// ---------------- projection ----------------
// grid 512 = (b = blk&7, n0). block 256 (4 waves). Stage x[64c][64n] in LDS
// (+1 pad col -> 2-way banks, free). Wave w owns rows r0=w*20..+20 of the 80
// output rows (f 0-7, g 8-15, h 16-79). r0 via readfirstlane -> all weight
// addressing is PROVABLY scalar -> s_load into SGPRs, zero VGPR cost.
// Rows processed 4 at a time: acc[4]+xv[4] ~ 25 live VGPRs -> no spills.
__global__ __launch_bounds__(256, 2) void proj_kernel(
    const float* __restrict__ x, const float* __restrict__ wq,
    const float* __restrict__ wk, const float* __restrict__ wv,
    unsigned short* __restrict__ f_t, unsigned short* __restrict__ g_t,
    unsigned short* __restrict__ h_out) {
  __shared__ float xs[64][65];

  const int tid = (int)threadIdx.x;
  const int wave = tid >> 6;
  const int lane = tid & 63;
  const int b = (int)blockIdx.x & 7;
  const int n0 = ((int)blockIdx.x >> 3) << 6;
  const float* xb = x + ((size_t)b << 18) + n0 + lane;

#pragma unroll
  for (int i = 0; i < 16; ++i) {
    const int c = wave + i * 4;
    xs[c][lane] = xb[(size_t)c << 12];
  }
  __syncthreads();

  const int r0 = __builtin_amdgcn_readfirstlane(wave * 20);

#pragma unroll
  for (int rb = 0; rb < 5; ++rb) {
    // scalar weight-row pointers for this 4-row group
    const float* w0;
    const float* w1;
    const float* w2;
    const float* w3;
    {
      const int ra = r0 + rb * 4;
#define WROW(rr) ((ra + rr) < 8 ? wq + ((ra + rr) << 6)            \
                : (ra + rr) < 16 ? wk + (((ra + rr) - 8) << 6)     \
                                 : wv + (((ra + rr) - 16) << 6))
      w0 = WROW(0); w1 = WROW(1); w2 = WROW(2); w3 = WROW(3);
#undef WROW
    }

    float a0 = 0.f, a1 = 0.f, a2 = 0.f, a3 = 0.f;
#pragma unroll 4
    for (int c4 = 0; c4 < 16; ++c4) {
      float xv[4];
#pragma unroll
      for (int j = 0; j < 4; ++j) xv[j] = xs[c4 * 4 + j][lane];
#pragma unroll
      for (int j = 0; j < 4; ++j) {
        a0 += w0[c4 * 4 + j] * xv[j];
        a1 += w1[c4 * 4 + j] * xv[j];
        a2 += w2[c4 * 4 + j] * xv[j];
        a3 += w3[c4 * 4 + j] * xv[j];
      }
    }

    const float av[4] = {a0, a1, a2, a3};
#pragma unroll
    for (int rr = 0; rr < 4; ++rr) {
      const int r = r0 + rb * 4 + rr;  // scalar -> uniform branch
      const unsigned short v = f2b(av[rr]);
      if (r < 8)
        f_t[((size_t)((b << 12) + n0 + lane) << 3) + r] = v;
      else if (r < 16)
        g_t[((size_t)((b << 12) + n0 + lane) << 3) + (r - 8)] = v;
      else
        h_out[(((size_t)(b * 64 + (r - 16))) << 12) + n0 + lane] = v;
    }
  }
}

// ---------------- flash attention, producer/consumer ----------------
// grid 512 = (b = blk&7 XCD-local, m-tile of 64), block 512 (8 waves).
// Producers 0-3: 32x32x16 score MFMA (K 8->16 zero-padded), exp, pack,
// swizzled P write to LDS (double-buffered, 1 barrier/tile).
// Consumers 4-7: 32c x 32m O tile, H from global (triple-buffered, 2-deep
// prefetch), swizzled conflict-free P b128 reads, 4 PV MFMAs.
// P_lds column swizzle: 16-short group g stored at g ^ ((ml>>3)&3) -> both
// b64 writes and b128 reads <=2-way bank aliasing (free).
__global__ __launch_bounds__(512, 4) void attn_kernel(
    const unsigned short* __restrict__ f_t, const unsigned short* __restrict__ g_t,
    const unsigned short* __restrict__ h, const float* __restrict__ x,
    const float* __restrict__ gamma, float* __restrict__ out) {
  __shared__ unsigned short P_lds[2][64][72];  // 18 KB
  __shared__ float lred[4][32];

  const int tid = (int)threadIdx.x;
  const int wave = tid >> 6;
  const int lane = tid & 63;
  const int ml = lane & 31;
  const int hh = lane >> 5;
  const int key = (ml >> 3) & 3;

  const int b = (int)blockIdx.x & 7;
  const int m0 = ((int)blockIdx.x >> 3) << 6;

  const unsigned short* fb = f_t + ((size_t)b << 15);
  const unsigned short* hb = h + ((size_t)b << 18);

  if (wave < 4) {
    // ================= producer =================
    const int nh = wave & 1, mh = wave >> 1;
    U128 G;
    G.u = make_uint4(0u, 0u, 0u, 0u);
    if (hh == 0)
      G.u = *(const uint4*)(g_t + ((size_t)((b << 12) + m0 + mh * 32 + ml) << 3));

    U128 Fa, Fb, Fn;
    Fa.u = *(const uint4*)(fb + ((size_t)(nh * 32 + ml) << 3));
    Fb.u = *(const uint4*)(fb + ((size_t)(64 + nh * 32 + ml) << 3));
    float lp = 0.f;

    unsigned short* prowb = &P_lds[0][mh * 32 + ml][0];

    for (int i = 0; i <= 64; ++i) {
      if (i < 64) {
        const int nnext = (((i + 2) & 63) << 6) + nh * 32 + ml;
        Fn.u = *(const uint4*)(fb + ((size_t)nnext << 3));

        f32x16 zz = {};
        f32x16 S = MFMA32(Fa.b, G.b, zz, 0, 0, 0);

        unsigned short* prow = prowb + (i & 1) * (64 * 72);
#pragma unroll
        for (int g2 = 0; g2 < 4; ++g2) {
          float e0 = __expf(S[4 * g2 + 0]);
          float e1 = __expf(S[4 * g2 + 1]);
          float e2 = __expf(S[4 * g2 + 2]);
          float e3 = __expf(S[4 * g2 + 3]);
          lp += (e0 + e1) + (e2 + e3);
          BPack lo, hi;
          lo.h2 = __float22bfloat162_rn(make_float2(e0, e1));
          hi.h2 = __float22bfloat162_rn(make_float2(e2, e3));
          uint2 w2;
          w2.x = lo.u;
          w2.y = hi.u;
          const int c = nh * 32 + 4 * hh + 8 * g2;              // logical col
          const int pc = (((c >> 4) ^ key) << 4) | (c & 15);    // swizzled
          *(uint2*)(prow + pc) = w2;
        }
        Fa = Fb;
        Fb = Fn;
      } else {
        float v = lp + __shfl_xor(lp, 32, 64);
        if (hh == 0) lred[wave][ml] = v;
      }
      __syncthreads();
    }
  } else {
    // ================= consumer =================
    const int cw = wave - 4;
    const int chc = cw & 1, mh = cw >> 1;
    const int row = mh * 32 + ml;
    const unsigned short* hrow = hb + ((size_t)(chc * 32 + ml) << 12) + 8 * hh;

    f32x16 O = {};
    U128 Ha[4], Hb2[4], Hn[4];
#pragma unroll
    for (int kk = 0; kk < 4; ++kk) {
      Ha[kk].u = *(const uint4*)(hrow + kk * 16);          // tile 0
      Hb2[kk].u = *(const uint4*)(hrow + 64 + kk * 16);    // tile 1
    }

    for (int i = 0; i <= 64; ++i) {
      if (i >= 1 && i < 64) {
        const int nn = (i + 1) & 63;
#pragma unroll
        for (int kk = 0; kk < 4; ++kk)
          Hn[kk].u = *(const uint4*)(hrow + (nn << 6) + kk * 16);
      }
      if (i >= 1) {
        const int par = (i - 1) & 1;
        const unsigned short* prow = &P_lds[par][row][0];
#pragma unroll
        for (int kk = 0; kk < 4; ++kk) {
          U128 p;
          p.u = *(const uint4*)(prow + (((kk ^ key) << 4) | (8 * hh)));
          O = MFMA32(Ha[kk].b, p.b, O, 0, 0, 0);
        }
#pragma unroll
        for (int kk = 0; kk < 4; ++kk) {
          Ha[kk] = Hb2[kk];
          Hb2[kk] = Hn[kk];
        }
      }
      __syncthreads();
    }

    // epilogue: out[b][c][m] = gamma/l[m] * O + x
    const float sc = gamma[0] / (lred[2 * mh][ml] + lred[2 * mh + 1][ml]);
#pragma unroll
    for (int reg = 0; reg < 16; ++reg) {
      const int c = chc * 32 + (reg & 3) + 8 * (reg >> 2) + 4 * hh;
      const size_t oi = (((size_t)b * 64 + c) << 12) + m0 + mh * 32 + ml;
      out[oi] = sc * O[reg] + x[oi];
    }
  }
}

extern "C" void kernel_launch(void* const* d_in, const int* in_sizes, int n_in,
                              void* d_out, int out_size, void* d_ws, size_t ws_size,
                              hipStream_t stream) {
  (void)in_sizes; (void)n_in; (void)out_size; (void)ws_size;
  const float* x = (const float*)d_in[0];
  const float* wq = (const float*)d_in[1];
  const float* wk = (const float*)d_in[2];
  const float* wv = (const float*)d_in[3];
  const float* gamma = (const float*)d_in[4];
  float* out = (float*)d_out;

  // workspace: f_t [8][4096][8] bf16, g_t same, h [8][64][4096] bf16 = 5.25 MB
  unsigned short* f_t = (unsigned short*)d_ws;
  unsigned short* g_t = f_t + (size_t)8 * 4096 * 8;
  unsigned short* h = g_t + (size_t)8 * 4096 * 8;

  proj_kernel<<<512, 256, 0, stream>>>(x, wq, wk, wv, f_t, g_t, h);
  attn_kernel<<<512, 512, 0, stream>>>(f_t, g_t, h, x, gamma, out);
}

// Round 5
// 135.424 us; speedup vs baseline: 2.0046x; 1.0981x over previous
//
#include <hip/hip_runtime.h>
#include <hip/hip_bf16.h>

typedef __bf16 bf16x8 __attribute__((ext_vector_type(8)));
typedef float f32x4 __attribute__((ext_vector_type(4)));
typedef float f32x16 __attribute__((ext_vector_type(16)));

#define MFMA16 __builtin_amdgcn_mfma_f32_16x16x32_bf16
#define MFMA32 __builtin_amdgcn_mfma_f32_32x32x16_bf16

__device__ __forceinline__ unsigned short f2b(float f) {
  unsigned int u = __float_as_uint(f);
  u += 0x7FFFu + ((u >> 16) & 1u);
  return (unsigned short)(u >> 16);
}

union U128 {
  uint4 u;
  unsigned short s[8];
  bf16x8 b;
};

union BPack {
  __hip_bfloat162 h2;
  unsigned u;
};

__device__ __forceinline__ unsigned packbf(float a, float b) {
  BPack p;
  p.h2 = __float22bfloat162_rn(make_float2(a, b));
  return p.u;
}

// ---------------- projection via MFMA ----------------
// grid 512 = (b = blk&7, n0 = 64-tile). block 256 (4 waves).
// Y[96 pad][4096] = W[96x64] X[64x4096] per batch, bf16 MFMA 16x16x32.
// xT: transposed bf16 x-tile in LDS, row n (128 B = 8 groups of 16 B),
//     group g stored at g ^ (n&7) (XOR swizzle: aligned, low-conflict).
// wT: [96][72] bf16 row-major (rows 80-95 never read: tile rt<5 only).
// Wave handles n-subtile nq=wave (16 cols) x 5 row-tiles x 2 k-passes.
__global__ __launch_bounds__(256, 2) void proj_kernel(
    const float* __restrict__ x, const float* __restrict__ wq,
    const float* __restrict__ wk, const float* __restrict__ wv_w,
    unsigned short* __restrict__ f_t, unsigned short* __restrict__ g_t,
    unsigned short* __restrict__ h_out) {
  __shared__ unsigned short xT[64 * 64];
  __shared__ unsigned short wT[96 * 72];

  const int tid = (int)threadIdx.x;
  const int wvp = tid >> 6;
  const int lane = tid & 63;
  const int b = (int)blockIdx.x & 7;
  const int n0 = ((int)blockIdx.x >> 3) << 6;

  // ---- stage xT: thread loads 16 c's for n=lane, packs, swizzled write ----
  {
    const float* xb = x + ((size_t)b << 18) + n0 + lane;
    const int c0 = wvp * 16;
    float xv[16];
#pragma unroll
    for (int cc = 0; cc < 16; ++cc) xv[cc] = xb[(size_t)(c0 + cc) << 12];
#pragma unroll
    for (int p = 0; p < 4; ++p) {
      const int c = c0 + 4 * p;
      uint2 d;
      d.x = packbf(xv[4 * p + 0], xv[4 * p + 1]);
      d.y = packbf(xv[4 * p + 2], xv[4 * p + 3]);
      const int g = c >> 3;
      const int idx = lane * 64 + (((g ^ (lane & 7)) << 3) | (((c >> 2) & 1) << 2));
      *(uint2*)&xT[idx] = d;
    }
  }
  // ---- stage wT (80 rows of 64, bf16) ----
#pragma unroll
  for (int i = 0; i < 20; ++i) {
    const int idx = i * 256 + tid;
    const float wval = (idx < 512) ? wq[idx]
                     : (idx < 1024) ? wk[idx - 512]
                                    : wv_w[idx - 1024];
    wT[(idx >> 6) * 72 + (idx & 63)] = f2b(wval);
  }
  __syncthreads();

  // ---- compute ----
  const int t = lane & 15, q = lane >> 4;
  const int nloc = wvp * 16 + t;
  U128 Bf[2];
#pragma unroll
  for (int kp = 0; kp < 2; ++kp) {
    const int g = kp * 4 + q;
    Bf[kp].u = *(const uint4*)&xT[nloc * 64 + ((g ^ (nloc & 7)) << 3)];
  }
  const int nabs = n0 + nloc;
#pragma unroll
  for (int rt = 0; rt < 5; ++rt) {
    f32x4 acc = {0.f, 0.f, 0.f, 0.f};
#pragma unroll
    for (int kp = 0; kp < 2; ++kp) {
      U128 Af;
      Af.u = *(const uint4*)&wT[(rt * 16 + t) * 72 + ((kp * 4 + q) << 3)];
      acc = MFMA16(Af.b, Bf[kp].b, acc, 0, 0, 0);
    }
#pragma unroll
    for (int reg = 0; reg < 4; ++reg) {
      const int r = rt * 16 + 4 * q + reg;
      const unsigned short v = f2b(acc[reg]);
      if (r < 8)
        f_t[((size_t)((b << 12) + nabs) << 3) + r] = v;
      else if (r < 16)
        g_t[((size_t)((b << 12) + nabs) << 3) + (r - 8)] = v;
      else
        h_out[((size_t)(b * 64 + (r - 16)) << 12) + nabs] = v;
    }
  }
}

// ---------------- flash attention: independent waves, no P-LDS ----------------
// grid 1024 = (b = blk&7, m32-item). block 256 (4 waves, 4 blocks/CU).
// Wave w: all 64 c x 32 m, n-quarter [w*1024, w*1024+1024) in 32-tiles.
// Per tile: score MFMA32 (K 8->16, zero G half), 16 expf, C->B transform
// via 4 __shfl_xor(32) on packed bf16 pairs, 4 PV MFMA32 (2 c-halves x 2 kt).
// End: one LDS reduction over the 4 waves' O-partials + denominators.
__global__ __launch_bounds__(256, 4) void attn_kernel(
    const unsigned short* __restrict__ f_t, const unsigned short* __restrict__ g_t,
    const unsigned short* __restrict__ h, const float* __restrict__ x,
    const float* __restrict__ gamma, float* __restrict__ out) {
  __shared__ float Opart[4][2048];  // [wave][c*32+m]
  __shared__ float lred[4][32];
  __shared__ float lsum[32];

  const int tid = (int)threadIdx.x;
  const int wave = tid >> 6;
  const int lane = tid & 63;
  const int ml = lane & 31;
  const int hh = lane >> 5;

  const int b = (int)blockIdx.x & 7;
  const int m32 = ((int)blockIdx.x >> 3) << 5;

  const unsigned short* fb = f_t + ((size_t)b << 15);
  const unsigned short* hb = h + ((size_t)b << 18);

  U128 G;
  G.u = make_uint4(0u, 0u, 0u, 0u);
  if (hh == 0) G.u = *(const uint4*)(g_t + ((size_t)((b << 12) + m32 + ml) << 3));

  f32x16 O0 = {}, O1 = {};
  float lp = 0.f;

  const int nbase = wave << 10;
  U128 F;
  F.u = *(const uint4*)(fb + ((size_t)(nbase + ml) << 3));

  for (int it = 0; it < 32; ++it) {
    const int n32 = nbase + (it << 5);

    // H A-fragments: [ct][kt], A[c][k=n]: c = ct*32+ml, n = n32+kt*16+8hh
    U128 H00, H01, H10, H11;
    {
      const unsigned short* hr0 = hb + ((size_t)(ml) << 12) + n32 + 8 * hh;
      const unsigned short* hr1 = hb + ((size_t)(32 + ml) << 12) + n32 + 8 * hh;
      H00.u = *(const uint4*)(hr0);
      H01.u = *(const uint4*)(hr0 + 16);
      H10.u = *(const uint4*)(hr1);
      H11.u = *(const uint4*)(hr1 + 16);
    }
    // prefetch next F
    U128 Fn = F;
    if (it < 31)
      Fn.u = *(const uint4*)(fb + ((size_t)(n32 + 32 + ml) << 3));

    const f32x16 z = {};
    f32x16 S = MFMA32(F.b, G.b, z, 0, 0, 0);
    F = Fn;

    float e[16];
#pragma unroll
    for (int r = 0; r < 16; ++r) e[r] = __expf(S[r]);
#pragma unroll
    for (int r = 0; r < 16; ++r) lp += e[r];

    // C->B transform: per kt, exchange packed bf16 pairs with lane^32
#pragma unroll
    for (int kt = 0; kt < 2; ++kt) {
      const unsigned A0 = packbf(e[8 * kt + 0], e[8 * kt + 1]);
      const unsigned A1 = packbf(e[8 * kt + 2], e[8 * kt + 3]);
      const unsigned B0 = packbf(e[8 * kt + 4], e[8 * kt + 5]);
      const unsigned B1 = packbf(e[8 * kt + 6], e[8 * kt + 7]);
      const unsigned s0 = hh ? A0 : B0;
      const unsigned s1 = hh ? A1 : B1;
      const unsigned r0 = (unsigned)__shfl_xor((int)s0, 32, 64);
      const unsigned r1 = (unsigned)__shfl_xor((int)s1, 32, 64);
      U128 P;
      P.u.x = hh ? r0 : A0;
      P.u.y = hh ? r1 : A1;
      P.u.z = hh ? B0 : r0;
      P.u.w = hh ? B1 : r1;
      if (kt == 0) {
        O0 = MFMA32(H00.b, P.b, O0, 0, 0, 0);
        O1 = MFMA32(H10.b, P.b, O1, 0, 0, 0);
      } else {
        O0 = MFMA32(H01.b, P.b, O0, 0, 0, 0);
        O1 = MFMA32(H11.b, P.b, O1, 0, 0, 0);
      }
    }
  }

  // wave-local denominator (both halves), then stash partials
  lp += __shfl_xor(lp, 32, 64);
  if (hh == 0) lred[wave][ml] = lp;
#pragma unroll
  for (int reg = 0; reg < 16; ++reg) {
    const int c0 = (reg & 3) + 8 * (reg >> 2) + 4 * hh;
    Opart[wave][c0 * 32 + ml] = O0[reg];
    Opart[wave][(32 + c0) * 32 + ml] = O1[reg];
  }
  __syncthreads();
  if (tid < 32)
    lsum[tid] = (lred[0][tid] + lred[1][tid]) + (lred[2][tid] + lred[3][tid]);
  __syncthreads();

  // epilogue: thread owns c = tid>>2, m = (tid&3)*8 .. +8
  const int c = tid >> 2;
  const int m0l = (tid & 3) << 3;
  const float gam = gamma[0];
  f32x4 a0, a1;
  {
    const int base = c * 32 + m0l;
    a0 = *(const f32x4*)&Opart[0][base];
    a1 = *(const f32x4*)&Opart[0][base + 4];
#pragma unroll
    for (int w = 1; w < 4; ++w) {
      a0 += *(const f32x4*)&Opart[w][base];
      a1 += *(const f32x4*)&Opart[w][base + 4];
    }
  }
  const f32x4 l0 = *(const f32x4*)&lsum[m0l];
  const f32x4 l1 = *(const f32x4*)&lsum[m0l + 4];
  const size_t oi = (((size_t)b * 64 + c) << 12) + m32 + m0l;
  f32x4 xo0 = *(const f32x4*)(x + oi);
  f32x4 xo1 = *(const f32x4*)(x + oi + 4);
#pragma unroll
  for (int j = 0; j < 4; ++j) {
    xo0[j] += gam / l0[j] * a0[j];
    xo1[j] += gam / l1[j] * a1[j];
  }
  *(f32x4*)(out + oi) = xo0;
  *(f32x4*)(out + oi + 4) = xo1;
}

extern "C" void kernel_launch(void* const* d_in, const int* in_sizes, int n_in,
                              void* d_out, int out_size, void* d_ws, size_t ws_size,
                              hipStream_t stream) {
  (void)in_sizes; (void)n_in; (void)out_size; (void)ws_size;
  const float* x = (const float*)d_in[0];
  const float* wq = (const float*)d_in[1];
  const float* wk = (const float*)d_in[2];
  const float* wv = (const float*)d_in[3];
  const float* gamma = (const float*)d_in[4];
  float* out = (float*)d_out;

  // workspace: f_t [8][4096][8] bf16, g_t same, h [8][64][4096] bf16 = 5.25 MB
  unsigned short* f_t = (unsigned short*)d_ws;
  unsigned short* g_t = f_t + (size_t)8 * 4096 * 8;
  unsigned short* h = g_t + (size_t)8 * 4096 * 8;

  proj_kernel<<<512, 256, 0, stream>>>(x, wq, wk, wv, f_t, g_t, h);
  attn_kernel<<<1024, 256, 0, stream>>>(f_t, g_t, h, x, gamma, out);
}